// Round 1
// baseline (405.360 us; speedup 1.0000x reference)
//
#include <hip/hip_runtime.h>

// LSTM classifier fused kernel. B=2048, T=256, F=64, H=128.
// 256 blocks x 512 threads; each block owns 8 batch rows for the whole
// sequence. Gate GEMM [16(8 real),192]x[192,512] per step via bf16 MFMA
// 16x16x32 with register-resident weights (96 VGPR/lane B-frags).
// c stays in per-thread registers; h round-trips LDS as bf16 (A-operand).

#define Bsz   2048
#define Tlen  256
#define Fdim  64
#define Hdim  128
#define G4    512            // 4*H
#define KPAD  200            // A-row stride in bf16 elems (192 + 8 pad; 100 dwords -> uniform banks)
#define BB    8              // batch rows per block
#define NTHREADS 512

using bf16x8 = __attribute__((ext_vector_type(8))) __bf16;
using f32x4  = __attribute__((ext_vector_type(4))) float;

__device__ __forceinline__ float fast_rcp(float x) {
#if __has_builtin(__builtin_amdgcn_rcpf)
    return __builtin_amdgcn_rcpf(x);
#else
    return 1.0f / x;
#endif
}
__device__ __forceinline__ float fast_exp2(float x) {
#if __has_builtin(__builtin_amdgcn_exp2f)
    return __builtin_amdgcn_exp2f(x);
#else
    return exp2f(x);
#endif
}
__device__ __forceinline__ float fsig(float x) {
    float e = fast_exp2(-1.4426950408889634f * x);
    return fast_rcp(1.0f + e);
}
__device__ __forceinline__ float ftanh(float x) {
    float e = fast_exp2(-2.8853900817779268f * x);   // exp(-2x)
    return (1.0f - e) * fast_rcp(1.0f + e);
}

__global__ __launch_bounds__(NTHREADS, 2)
void lstm_fused(const float* __restrict__ x,
                const float* __restrict__ W_ih,
                const float* __restrict__ W_hh,
                const float* __restrict__ b_ih,
                const float* __restrict__ b_hh,
                const float* __restrict__ W1,
                const float* __restrict__ b1,
                const float* __restrict__ W2,
                const float* __restrict__ b2,
                float* __restrict__ out)
{
    __shared__ __bf16 Alds[16 * KPAD];     // A operand: [row 0..15][x(64) | h(128) | pad]
    __shared__ float  gatesL[BB * G4];     // gates exchange (rows 0..7), reused for h_last
    __shared__ float  zbuf[BB * 32];       // head hidden

    const int tid  = threadIdx.x;
    const int wave = tid >> 6;
    const int lane = tid & 63;
    const int quad = lane >> 4;
    const int l16  = lane & 15;
    const int n0   = wave * 64;            // this wave's gate-column slice base
    const int b0   = blockIdx.x * BB;

    // ---- B fragments (weights), loop-invariant, in registers ----
    // B[k][n] = W[n][k]; lane holds k = kt*32 + quad*8 + j (j=0..7), n = n0+nt*16+l16
    bf16x8 bw[6][4];
    #pragma unroll
    for (int kt = 0; kt < 6; ++kt) {
        const int k0 = kt * 32 + quad * 8;
        #pragma unroll
        for (int nt = 0; nt < 4; ++nt) {
            const int n = n0 + nt * 16 + l16;
            const float* p = (kt < 2) ? (W_ih + n * Fdim + k0)
                                      : (W_hh + n * Hdim + (k0 - Fdim));
            float4 lo = *(const float4*)p;
            float4 hi = *(const float4*)(p + 4);
            bf16x8 r;
            r[0]=(__bf16)lo.x; r[1]=(__bf16)lo.y; r[2]=(__bf16)lo.z; r[3]=(__bf16)lo.w;
            r[4]=(__bf16)hi.x; r[5]=(__bf16)hi.y; r[6]=(__bf16)hi.z; r[7]=(__bf16)hi.w;
            bw[kt][nt] = r;
        }
    }
    float biasv[4];
    #pragma unroll
    for (int nt = 0; nt < 4; ++nt) {
        const int n = n0 + nt * 16 + l16;
        biasv[nt] = b_ih[n] + b_hh[n];
    }

    // ---- x streaming: thread -> (row bx, feature fx), one float per step ----
    const int bx = tid >> 6;               // 0..7
    const int fx = tid & 63;
    const float* xp = x + (size_t)(b0 + bx) * (Tlen * Fdim) + fx;

    // zero A (h0 = 0, padding rows = 0), stage x_0, prefetch x_1
    for (int i = tid; i < 16 * KPAD; i += NTHREADS) Alds[i] = (__bf16)0.0f;
    float x0  = xp[0];
    float xr1 = xp[Fdim];                  // x_{t+1} pipeline register
    __syncthreads();
    Alds[bx * KPAD + fx] = (__bf16)x0;
    __syncthreads();

    // elementwise ownership: thread -> (b_e0, j_e) and (b_e0+4, j_e); c in regs
    float carr[2] = {0.0f, 0.0f};
    const int j_e  = tid & 127;
    const int b_e0 = tid >> 7;             // 0..3

    for (int t = 0; t < Tlen; ++t) {
        float xnext = 0.0f;
        if (t + 2 < Tlen) xnext = xp[(t + 2) * Fdim];   // 2-deep prefetch

        // A fragments from LDS: lane -> A[row=l16][k=kt*32+quad*8 .. +7]
        bf16x8 af[6];
        #pragma unroll
        for (int kt = 0; kt < 6; ++kt)
            af[kt] = *(const bf16x8*)&Alds[l16 * KPAD + kt * 32 + quad * 8];

        #pragma unroll
        for (int nt = 0; nt < 4; ++nt) {
            f32x4 acc = {biasv[nt], biasv[nt], biasv[nt], biasv[nt]};
            #pragma unroll
            for (int kt = 0; kt < 6; ++kt)
                acc = __builtin_amdgcn_mfma_f32_16x16x32_bf16(af[kt], bw[kt][nt], acc, 0, 0, 0);
            // C/D: row = quad*4 + reg, col = l16; only rows 0..7 are real
            if (quad < 2) {
                const int col  = n0 + nt * 16 + l16;
                const int rowb = quad * 4;
                #pragma unroll
                for (int r = 0; r < 4; ++r)
                    gatesL[(rowb + r) * G4 + col] = acc[r];
            }
        }
        __syncthreads();   // gates visible; MFMA done reading Alds

        #pragma unroll
        for (int it = 0; it < 2; ++it) {
            const int b = b_e0 + 4 * it;
            const float* g = gatesL + b * G4 + j_e;
            float gi = g[0], gf = g[128], gg = g[256], go = g[384];
            float iv = fsig(gi), fv = fsig(gf), gv = ftanh(gg), ov = fsig(go);
            float c = fv * carr[it] + iv * gv;
            carr[it] = c;
            float h = ov * ftanh(c);
            Alds[b * KPAD + Fdim + j_e] = (__bf16)h;       // A-operand for t+1
            if (t == Tlen - 1) gatesL[b * G4 + j_e] = h;   // fp32 h_last for head
        }
        if (t + 1 < Tlen) Alds[bx * KPAD + fx] = (__bf16)xr1;
        xr1 = xnext;
        __syncthreads();   // Alds ready for next step
    }

    // ---- head: z = relu(h @ W1^T + b1); out = sigmoid(z @ W2^T + b2) ----
    if (tid < 256) {
        const int b = tid >> 5, n = tid & 31;
        const float4* w4 = (const float4*)(W1 + n * Hdim);
        const float4* h4 = (const float4*)(gatesL + b * G4);
        float s = b1[n];
        #pragma unroll
        for (int kk = 0; kk < Hdim / 4; ++kk) {
            float4 w = w4[kk];
            float4 h = h4[kk];
            s += w.x * h.x + w.y * h.y + w.z * h.z + w.w * h.w;
        }
        zbuf[b * 32 + n] = fmaxf(s, 0.0f);
    }
    __syncthreads();
    if (tid < 8) {
        float s = b2[0];
        #pragma unroll
        for (int n = 0; n < 32; ++n) s += zbuf[tid * 32 + n] * W2[n];
        out[b0 + tid] = fsig(s);
    }
}

extern "C" void kernel_launch(void* const* d_in, const int* in_sizes, int n_in,
                              void* d_out, int out_size, void* d_ws, size_t ws_size,
                              hipStream_t stream) {
    const float* x    = (const float*)d_in[0];
    const float* W_ih = (const float*)d_in[1];
    const float* W_hh = (const float*)d_in[2];
    const float* b_ih = (const float*)d_in[3];
    const float* b_hh = (const float*)d_in[4];
    const float* W1   = (const float*)d_in[5];
    const float* b1   = (const float*)d_in[6];
    const float* W2   = (const float*)d_in[7];
    const float* b2   = (const float*)d_in[8];
    float* out = (float*)d_out;

    dim3 grid(Bsz / BB), block(NTHREADS);
    lstm_fused<<<grid, block, 0, stream>>>(x, W_ih, W_hh, b_ih, b_hh, W1, b1, W2, b2, out);
}